// Round 17
// baseline (141.960 us; speedup 1.0000x reference)
//
#include <hip/hip_runtime.h>

#define NCTX 3
#define B 8
#define CC 128
#define CF 256
#define H 64
#define W 64
#define HW 4096
#define YX 16384   // (2H)*(2W)

// workspace layout (float offsets)
#define WS_BIAS  8388608    // bias448 (448 floats)
#define WS_WALL  8454144    // bf16 Wall hi: 8*4*448*8 = 114688 ushorts
#define WS_MSP   8552960    // bf16 msP hi: 8*66*32*66*8 = 8921088 ushorts
#define WS_WB    13013504   // bf16 Wb: 9*8*4*128*8 = 294912 ushorts
#define WS_WALLO 13160960   // bf16 Wall lo: 114688 ushorts (end 13218304)

typedef __attribute__((ext_vector_type(8))) short bf16x8;
typedef __attribute__((ext_vector_type(4))) float f32x4;
typedef __attribute__((ext_vector_type(8))) unsigned short u16x8;

__device__ __forceinline__ unsigned short f2b(float f) {
    union { float f; unsigned u; } c; c.f = f;
    unsigned u = c.u + 0x7FFFu + ((c.u >> 16) & 1u);
    return (unsigned short)(u >> 16);
}
__device__ __forceinline__ float b2f(unsigned short u) {
    union { unsigned u; float f; } c; c.u = ((unsigned)u) << 16;
    return c.f;
}

// ---------------- K0: ALL prepasses (block-range dispatch) ----------------
__global__ __launch_bounds__(256) void k0(
    const float* __restrict__ Wc_w, const float* __restrict__ Wc_b,
    const float* __restrict__ Wf_w, const float* __restrict__ Wf_b,
    const float* __restrict__ Wk_w, const float* __restrict__ Wk_b,
    const float* __restrict__ Wv, const float* __restrict__ ms,
    unsigned short* __restrict__ Wall, unsigned short* __restrict__ Wallo,
    float* __restrict__ bias448, unsigned short* __restrict__ Wb,
    unsigned short* __restrict__ msP) {
    __shared__ float Ls[32][65];
    int blk = blockIdx.x;
    int t = threadIdx.x;
    if (blk < 448) {
        int o = blk * 256 + t;                    // 114688
        int ci8 = o & 7;
        int idx = o >> 3;                         // sc4*448 + row
        int row = idx % 448;
        int sc4 = idx / 448;                      // s*4 + c4
        int f = (sc4 >> 2) * 32 + (sc4 & 3) * 8 + ci8;
        float w;
        if (row < 128) {
            float s = 0.f;
            for (int o2 = 0; o2 < 128; ++o2) s += Wc_w[o2 * 128 + row] * Wf_w[o2 * 256 + f];
            w = s;
        } else if (row < 384) {
            int p = (row - 128) >> 1;
            w = (row & 1) ? Wk_w[p * 256 + f] : Wf_w[p * 256 + f];
        } else if (row == 384) {
            float s = 0.f;
            for (int o2 = 0; o2 < 128; ++o2) s += Wc_b[o2] * Wf_w[o2 * 256 + f];
            w = s;
        } else w = 0.f;
        unsigned short hi = f2b(w);
        Wall[o] = hi;
        Wallo[o] = f2b(w - b2f(hi));
        if (o < 448) {
            float bb;
            if (o < 128) {
                float s = 0.f;
                for (int o2 = 0; o2 < 128; ++o2) s += Wc_w[o2 * 128 + o] * Wf_b[o2];
                bb = s;
            } else if (o < 384) {
                int p = (o - 128) >> 1;
                bb = (o & 1) ? Wk_b[p] : Wf_b[p];
            } else if (o == 384) {
                float s = 0.f;
                for (int o2 = 0; o2 < 128; ++o2) s += Wc_b[o2] * Wf_b[o2];
                bb = s;
            } else if (o == 385) bb = -1.f;
            else bb = 0.f;
            bias448[o] = bb;
        }
    } else if (blk < 1600) {
        int o = (blk - 448) * 256 + t;            // 294912
        int ci8 = o & 7;
        int co  = (o >> 3) & 127;
        int c4  = (o >> 10) & 3;
        int s   = (o >> 12) & 7;
        int khw = o >> 15;                        // [0,9)
        int ci  = s * 32 + c4 * 8 + ci8;
        int kh  = khw / 3, kw = khw - kh * 3;
        Wb[o] = f2b(Wv[((co * 256 + ci) * 3 + kh) * 3 + kw]);
    } else if (blk < 1860) {
        int i = (blk - 1600) * 256 + t;           // 66560 exactly
        if (i < 66560) {
            size_t off;
            if (i < 33792) {          // rows y=0,65
                int x = i % 66; int r = i / 66;
                int g = r & 31, rowi = (r >> 5) & 1, b = r >> 6;
                off = ((((size_t)b * 66 + rowi * 65) * 32) + g) * 66 + x;
            } else {                  // cols x=0,65 for y=1..64
                int k = i - 33792;
                int xi = k & 1; int g = (k >> 1) & 31; int y1 = (k >> 6) & 63; int b = k >> 12;
                off = ((((size_t)b * 66 + (y1 + 1)) * 32) + g) * 66 + xi * 65;
            }
            *(u16x8*)&msP[off * 8] = (u16x8){0, 0, 0, 0, 0, 0, 0, 0};
        }
    } else {
        int local = blk - 1860;        // 4096 = 8b * 64h * 8s
        int s = local & 7;
        int h = (local >> 3) & 63;
        int b = local >> 9;
        const float* src = ms + ((size_t)b * 256 + s * 32) * HW + h * 64;
        for (int l = t; l < 2048; l += 256) {
            int ci = l >> 6, w = l & 63;
            Ls[ci][w] = src[ci * HW + w];
        }
        __syncthreads();
        int w = t & 63, gi = t >> 6;   // gi in [0,4)
        u16x8 vh;
#pragma unroll
        for (int j = 0; j < 8; ++j) vh[j] = f2b(Ls[gi * 8 + j][w]);
        size_t offH = ((((size_t)b * 66 + (h + 1)) * 32) + (s * 4 + gi)) * 66 + (w + 1);
        *(u16x8*)&msP[offH * 8] = vh;
    }
}

// ---------------- KFULL: fused k1m + k2m + k3, one (b,h) tile per block ----------
// grid 512 = 8b*64h, block 512 (8 waves), LDS 51.7 KB -> 3 blocks/CU (24 waves).
// r16 lever: LDS diet (phase B stage single-buffered 25.3->12.7 KB; phase-C
// part[] moved into the dead stage region). Phases A and C byte-identical to
// the r11/r16 champion. +50% TLP is the mechanism; intra-block B-overlap traded
// for inter-block overlap.
__global__ __launch_bounds__(512, 4) void kfull(
    const float* __restrict__ ms, const unsigned short* __restrict__ msP,
    const unsigned short* __restrict__ Wall, const unsigned short* __restrict__ Wallo,
    const float* __restrict__ bias448, const unsigned short* __restrict__ Wb,
    const float* __restrict__ Wv_b, const float* __restrict__ ctx,
    float* __restrict__ out) {
    __shared__ unsigned char smem[51712] __attribute__((aligned(16)));
    unsigned short* qtS16 = (unsigned short*)smem;              // [128c][64px]
    unsigned short* vS16  = (unsigned short*)(smem + 16384);    // [128c][64px]
    // stage region [32768, 49152): phase A dbuf (16 KB) / phase B single-buf
    // (12.7 KB) / phase C part[8][128] (4 KB)
    float* biasS = (float*)(smem + 49152);       // 448 floats
    float* biasB = (float*)(smem + 50944);       // 128 floats
    float* logitS = (float*)(smem + 50944);      // aliases biasB (dead by phase C)
    float* lmS   = (float*)(smem + 51456);       // 64 floats
    float (*part)[128] = (float (*)[128])(smem + 32768);

    int t = threadIdx.x;
    int lane = t & 63, wid = t >> 6;
    int c4l = lane >> 4, lrow = lane & 15;
    int b = blockIdx.x >> 6, h = blockIdx.x & 63;

    // ================= Phase A: k1m =================
    {
        auto Bs = (unsigned short (*)[2][4][64][8])(smem + 32768);  // [buf][plane][c4][x][ci8]
        int wm = wid >> 1, wn = wid & 1;
        int xs = t & 63, g4 = t >> 6;              // stage role: x, 4-ci group
        int c4w = g4 >> 1, sub = g4 & 1;
        const float* msb = ms + ((size_t)b * 256 + g4 * 4) * HW + h * 64 + xs;
        for (int i = t; i < 448; i += 512) biasS[i] = bias448[i];
        if (t < 128) biasB[t] = Wv_b[t];
        if (t < 64) lmS[t] = 0.f;

        f32x4 acc[7][2];
#pragma unroll
        for (int mf = 0; mf < 7; ++mf)
#pragma unroll
            for (int nf = 0; nf < 2; ++nf) acc[mf][nf] = (f32x4){0.f, 0.f, 0.f, 0.f};

        const bf16x8* Whip = (const bf16x8*)Wall;
        const bf16x8* Wlop = (const bf16x8*)Wallo;

#define CVT_WRITE(bufv, F0, F1, F2, F3) do {                                    \
        unsigned short h0 = f2b(F0), h1 = f2b(F1), h2 = f2b(F2), h3 = f2b(F3);  \
        unsigned short q0 = f2b((F0) - b2f(h0)), q1 = f2b((F1) - b2f(h1));      \
        unsigned short q2 = f2b((F2) - b2f(h2)), q3 = f2b((F3) - b2f(h3));      \
        uint2 hw, lw;                                                           \
        hw.x = (unsigned)h0 | ((unsigned)h1 << 16);                             \
        hw.y = (unsigned)h2 | ((unsigned)h3 << 16);                             \
        lw.x = (unsigned)q0 | ((unsigned)q1 << 16);                             \
        lw.y = (unsigned)q2 | ((unsigned)q3 << 16);                             \
        *(uint2*)&Bs[bufv][0][c4w][xs][sub * 4] = hw;                           \
        *(uint2*)&Bs[bufv][1][c4w][xs][sub * 4] = lw;                           \
    } while (0)

        {
            float f0 = msb[0], f1 = msb[HW], f2 = msb[2 * HW], f3 = msb[3 * HW];
            CVT_WRITE(0, f0, f1, f2, f3);
        }
        __syncthreads();

        for (int s = 0; s < 8; ++s) {
            int cur = s & 1;
            float fn0, fn1, fn2, fn3;
            if (s < 7) {
                const float* p = msb + (size_t)(s + 1) * 32 * HW;
                fn0 = p[0]; fn1 = p[HW]; fn2 = p[2 * HW]; fn3 = p[3 * HW];
            }
            bf16x8 bh[2], bl[2];
#pragma unroll
            for (int nf = 0; nf < 2; ++nf) {
                int x = wn * 32 + nf * 16 + lrow;
                bh[nf] = *(const bf16x8*)&Bs[cur][0][c4l][x][0];
                bl[nf] = *(const bf16x8*)&Bs[cur][1][c4l][x][0];
            }
#pragma unroll
            for (int mf = 0; mf < 7; ++mf) {
                size_t widx = (size_t)(s * 4 + c4l) * 448 + wm * 112 + mf * 16 + lrow;
                bf16x8 ah = Whip[widx];
                bf16x8 al = Wlop[widx];
#pragma unroll
                for (int nf = 0; nf < 2; ++nf) {
                    acc[mf][nf] = __builtin_amdgcn_mfma_f32_16x16x32_bf16(ah, bh[nf], acc[mf][nf], 0, 0, 0);
                    acc[mf][nf] = __builtin_amdgcn_mfma_f32_16x16x32_bf16(ah, bl[nf], acc[mf][nf], 0, 0, 0);
                    acc[mf][nf] = __builtin_amdgcn_mfma_f32_16x16x32_bf16(al, bh[nf], acc[mf][nf], 0, 0, 0);
                }
            }
            if (s < 7) CVT_WRITE(cur ^ 1, fn0, fn1, fn2, fn3);
            __syncthreads();
        }
#undef CVT_WRITE

        int px0 = wn * 32;
        float lmp[2] = {0.f, 0.f};
#pragma unroll
        for (int mf = 0; mf < 7; ++mf) {
            int base = wm * 112 + mf * 16;
            int r0 = base + c4l * 4;
            if (base < 128) {
#pragma unroll
                for (int nf = 0; nf < 2; ++nf) {
                    int x = px0 + nf * 16 + lrow;
                    f32x4 v = acc[mf][nf];
#pragma unroll
                    for (int j = 0; j < 4; ++j)
                        qtS16[(r0 + j) * 64 + x] = f2b(v[j] + biasS[r0 + j]);
                }
            } else {
                float b0 = biasS[r0], b1 = biasS[r0 + 1], b2 = biasS[r0 + 2], b3 = biasS[r0 + 3];
#pragma unroll
                for (int nf = 0; nf < 2; ++nf) {
                    f32x4 v = acc[mf][nf];
                    lmp[nf] += (v[0] + b0) * (v[1] + b1) + (v[2] + b2) * (v[3] + b3);
                }
            }
        }
        if (wm != 0) {
#pragma unroll
            for (int nf = 0; nf < 2; ++nf) {
                lmp[nf] += __shfl_xor(lmp[nf], 16);
                lmp[nf] += __shfl_xor(lmp[nf], 32);
            }
            if (c4l == 0) {
#pragma unroll
                for (int nf = 0; nf < 2; ++nf)
                    atomicAdd(&lmS[px0 + nf * 16 + lrow], lmp[nf]);
            }
        }
    }

    // ================= Phase B: k2m (single-buffered stage) =================
    {
        unsigned short* Bs = (unsigned short*)(smem + 32768);   // [792 chunks * 8]
        int wm = wid >> 1, wn = wid & 1;

        f32x4 acc[2][2];
#pragma unroll
        for (int mf = 0; mf < 2; ++mf)
#pragma unroll
            for (int nf = 0; nf < 2; ++nf) acc[mf][nf] = (f32x4){0.f, 0.f, 0.f, 0.f};

        const bf16x8* Wbp = (const bf16x8*)Wb;

#define STAGE2(sv) do {                                                             \
        for (int iter = 0; iter < 2; ++iter) {                                      \
            int q0 = iter * 512 + (wid << 6);                                       \
            int q = q0 + lane;                                                      \
            if (q < 792) {                                                          \
                int rc = q / 66; int x = q - rc * 66;                               \
                int r = rc >> 2, c4 = rc & 3;                                       \
                int y = h + r;                      /* msP rows h-1..h+1 */         \
                const unsigned short* gp = msP +                                    \
                    (((((size_t)b * 66 + y) * 32) + ((sv) * 4 + c4)) * 66 + x) * 8; \
                unsigned short* lp = &Bs[q0 * 8];                                   \
                __builtin_amdgcn_global_load_lds(                                   \
                    (const __attribute__((address_space(1))) void*)gp,              \
                    (__attribute__((address_space(3))) void*)lp, 16, 0, 0);         \
            }                                                                       \
        }                                                                           \
    } while (0)

        __syncthreads();   // phase-A stage region dead

        for (int s = 0; s < 8; ++s) {
            STAGE2(s);
            __syncthreads();
#pragma unroll
            for (int khw = 0; khw < 9; ++khw) {
                int kh = khw / 3, kw = khw - 3 * (khw / 3);
                bf16x8 a[2];
#pragma unroll
                for (int mf = 0; mf < 2; ++mf)
                    a[mf] = Wbp[((khw * 8 + s) * 4 + c4l) * 128 + wm * 32 + mf * 16 + lrow];
                bf16x8 bf[2];
#pragma unroll
                for (int nf = 0; nf < 2; ++nf) {
                    int chunk = (kh * 4 + c4l) * 66 + wn * 32 + nf * 16 + lrow + kw;
                    bf[nf] = *(const bf16x8*)&Bs[chunk * 8];
                }
#pragma unroll
                for (int mf = 0; mf < 2; ++mf)
#pragma unroll
                    for (int nf = 0; nf < 2; ++nf)
                        acc[mf][nf] = __builtin_amdgcn_mfma_f32_16x16x32_bf16(
                            a[mf], bf[nf], acc[mf][nf], 0, 0, 0);
            }
            __syncthreads();
        }
#undef STAGE2

#pragma unroll
        for (int mf = 0; mf < 2; ++mf) {
            int co0 = wm * 32 + mf * 16 + c4l * 4;
#pragma unroll
            for (int nf = 0; nf < 2; ++nf) {
                int x = wn * 32 + nf * 16 + lrow;
                f32x4 v = acc[mf][nf];
#pragma unroll
                for (int j = 0; j < 4; ++j)
                    vS16[(co0 + j) * 64 + x] = f2b(v[j] + biasB[co0 + j]);
            }
        }
    }

    // ================= Phase C: online-softmax combine =================
    __syncthreads();   // qtS, vS, lmS all visible
    {
        const unsigned* qtS32 = (const unsigned*)qtS16;
        const unsigned* vS32  = (const unsigned*)vS16;
        int xg = t & 31, cq = t >> 5;     // 32 x-groups of 4, 16 c-groups of 8
        int wv = t >> 6;
        unsigned qp[8], vp[8];
#pragma unroll
        for (int j = 0; j < 8; ++j) {
            qp[j] = qtS32[(cq * 8 + j) * 32 + xg];
            vp[j] = vS32[(cq * 8 + j) * 32 + xg];
        }
        float lmx0 = lmS[xg * 2], lmx1 = lmS[xg * 2 + 1];

        for (int yi = 0; yi < 2; ++yi) {
            int y = 2 * h + yi;
            float m[4] = {lmx0, lmx0, lmx1, lmx1};
            float sum[4] = {1.f, 1.f, 1.f, 1.f};
            float4 oa[8];
#pragma unroll
            for (int j = 0; j < 8; ++j) {
                float vx = b2f((unsigned short)(vp[j] & 0xffffu));
                float vy = b2f((unsigned short)(vp[j] >> 16));
                oa[j] = (float4){vx, vx, vy, vy};
            }
#pragma unroll 1
            for (int n = 0; n < 3; ++n) {
                const float* cb = ctx + ((size_t)(n * 8 + b) * 128 + cq * 8) * YX
                                  + (size_t)y * 128 + xg * 4;
                float4 cx[8];
#pragma unroll
                for (int j = 0; j < 8; ++j) cx[j] = *(const float4*)&cb[(size_t)j * YX];
                float lp[4] = {0.f, 0.f, 0.f, 0.f};
#pragma unroll
                for (int j = 0; j < 8; ++j) {
                    float qx = b2f((unsigned short)(qp[j] & 0xffffu));
                    float qy = b2f((unsigned short)(qp[j] >> 16));
                    lp[0] += cx[j].x * qx;
                    lp[1] += cx[j].y * qx;
                    lp[2] += cx[j].z * qy;
                    lp[3] += cx[j].w * qy;
                }
#pragma unroll
                for (int xl = 0; xl < 4; ++xl) lp[xl] += __shfl_xor(lp[xl], 32);
                __syncthreads();   // prior logitS reads / part usage complete
                if (lane < 32) {
#pragma unroll
                    for (int xl = 0; xl < 4; ++xl) part[wv][xg * 4 + xl] = lp[xl];
                }
                __syncthreads();
                if (t < 128) {
                    float s = 0.f;
#pragma unroll
                    for (int w = 0; w < 8; ++w) s += part[w][t];
                    logitS[t] = s;
                }
                __syncthreads();
                float f[4], e[4];
#pragma unroll
                for (int xl = 0; xl < 4; ++xl) {
                    float ln = logitS[xg * 4 + xl];
                    float nm = fmaxf(m[xl], ln);
                    f[xl] = __expf(m[xl] - nm);
                    e[xl] = __expf(ln - nm);
                    sum[xl] = sum[xl] * f[xl] + e[xl];
                    m[xl] = nm;
                }
#pragma unroll
                for (int j = 0; j < 8; ++j) {
                    oa[j].x = oa[j].x * f[0] + e[0] * cx[j].x;
                    oa[j].y = oa[j].y * f[1] + e[1] * cx[j].y;
                    oa[j].z = oa[j].z * f[2] + e[2] * cx[j].z;
                    oa[j].w = oa[j].w * f[3] + e[3] * cx[j].w;
                }
            }
            float r0 = 1.f / sum[0], r1 = 1.f / sum[1], r2 = 1.f / sum[2], r3 = 1.f / sum[3];
            float* obase = out + ((size_t)b * 128 + cq * 8) * YX + (size_t)y * 128 + xg * 4;
#pragma unroll
            for (int j = 0; j < 8; ++j) {
                float4 o;
                o.x = oa[j].x * r0;
                o.y = oa[j].y * r1;
                o.z = oa[j].z * r2;
                o.w = oa[j].w * r3;
                *(float4*)&obase[(size_t)j * YX] = o;
            }
        }
    }
}

extern "C" void kernel_launch(void* const* d_in, const int* in_sizes, int n_in,
                              void* d_out, int out_size, void* d_ws, size_t ws_size,
                              hipStream_t stream) {
    const float* ctx  = (const float*)d_in[0];
    const float* ms   = (const float*)d_in[1];
    const float* Wc_w = (const float*)d_in[2];
    const float* Wc_b = (const float*)d_in[3];
    const float* Wf_w = (const float*)d_in[4];
    const float* Wf_b = (const float*)d_in[5];
    const float* Wk_w = (const float*)d_in[6];
    const float* Wk_b = (const float*)d_in[7];
    const float* Wv_w = (const float*)d_in[8];
    const float* Wv_b = (const float*)d_in[9];
    float* out = (float*)d_out;
    float* ws = (float*)d_ws;
    float* bias448 = ws + WS_BIAS;
    unsigned short* Wallp  = (unsigned short*)(ws + WS_WALL);
    unsigned short* Wallop = (unsigned short*)(ws + WS_WALLO);
    unsigned short* msPp   = (unsigned short*)(ws + WS_MSP);
    unsigned short* Wbp    = (unsigned short*)(ws + WS_WB);

    hipLaunchKernelGGL(k0, dim3(5956), dim3(256), 0, stream, Wc_w, Wc_b, Wf_w, Wf_b,
                       Wk_w, Wk_b, Wv_w, ms, Wallp, Wallop, bias448, Wbp, msPp);
    hipLaunchKernelGGL(kfull, dim3(512), dim3(512), 0, stream, ms, msPp, Wallp, Wallop,
                       bias448, Wbp, Wv_b, ctx, out);
}

// Round 18
// 134.937 us; speedup vs baseline: 1.0520x; 1.0520x over previous
//
#include <hip/hip_runtime.h>

#define NCTX 3
#define B 8
#define CC 128
#define CF 256
#define H 64
#define W 64
#define HW 4096
#define YX 16384   // (2H)*(2W)

// workspace layout (float offsets)
#define WS_BIAS  8388608    // bias448 (448 floats)
#define WS_WALL  8454144    // bf16 Wall hi: 8*4*448*8 = 114688 ushorts
#define WS_MSP   8552960    // bf16 msP hi: 8*66*32*66*8 = 8921088 ushorts
#define WS_WB    13013504   // bf16 Wb: 9*8*4*128*8 = 294912 ushorts
#define WS_WALLO 13160960   // bf16 Wall lo: 114688 ushorts (end 13218304)

typedef __attribute__((ext_vector_type(8))) short bf16x8;
typedef __attribute__((ext_vector_type(4))) float f32x4;
typedef __attribute__((ext_vector_type(8))) unsigned short u16x8;

__device__ __forceinline__ unsigned short f2b(float f) {
    union { float f; unsigned u; } c; c.f = f;
    unsigned u = c.u + 0x7FFFu + ((c.u >> 16) & 1u);
    return (unsigned short)(u >> 16);
}
__device__ __forceinline__ float b2f(unsigned short u) {
    union { unsigned u; float f; } c; c.u = ((unsigned)u) << 16;
    return c.f;
}

// ---------------- K0: ALL prepasses (block-range dispatch) ----------------
__global__ __launch_bounds__(256) void k0(
    const float* __restrict__ Wc_w, const float* __restrict__ Wc_b,
    const float* __restrict__ Wf_w, const float* __restrict__ Wf_b,
    const float* __restrict__ Wk_w, const float* __restrict__ Wk_b,
    const float* __restrict__ Wv, const float* __restrict__ ms,
    unsigned short* __restrict__ Wall, unsigned short* __restrict__ Wallo,
    float* __restrict__ bias448, unsigned short* __restrict__ Wb,
    unsigned short* __restrict__ msP) {
    __shared__ float Ls[32][65];
    int blk = blockIdx.x;
    int t = threadIdx.x;
    if (blk < 448) {
        int o = blk * 256 + t;                    // 114688
        int ci8 = o & 7;
        int idx = o >> 3;                         // sc4*448 + row
        int row = idx % 448;
        int sc4 = idx / 448;                      // s*4 + c4
        int f = (sc4 >> 2) * 32 + (sc4 & 3) * 8 + ci8;
        float w;
        if (row < 128) {
            float s = 0.f;
            for (int o2 = 0; o2 < 128; ++o2) s += Wc_w[o2 * 128 + row] * Wf_w[o2 * 256 + f];
            w = s;
        } else if (row < 384) {
            int p = (row - 128) >> 1;
            w = (row & 1) ? Wk_w[p * 256 + f] : Wf_w[p * 256 + f];
        } else if (row == 384) {
            float s = 0.f;
            for (int o2 = 0; o2 < 128; ++o2) s += Wc_b[o2] * Wf_w[o2 * 256 + f];
            w = s;
        } else w = 0.f;
        unsigned short hi = f2b(w);
        Wall[o] = hi;
        Wallo[o] = f2b(w - b2f(hi));
        if (o < 448) {
            float bb;
            if (o < 128) {
                float s = 0.f;
                for (int o2 = 0; o2 < 128; ++o2) s += Wc_w[o2 * 128 + o] * Wf_b[o2];
                bb = s;
            } else if (o < 384) {
                int p = (o - 128) >> 1;
                bb = (o & 1) ? Wk_b[p] : Wf_b[p];
            } else if (o == 384) {
                float s = 0.f;
                for (int o2 = 0; o2 < 128; ++o2) s += Wc_b[o2] * Wf_b[o2];
                bb = s;
            } else if (o == 385) bb = -1.f;
            else bb = 0.f;
            bias448[o] = bb;
        }
    } else if (blk < 1600) {
        int o = (blk - 448) * 256 + t;            // 294912
        int ci8 = o & 7;
        int co  = (o >> 3) & 127;
        int c4  = (o >> 10) & 3;
        int s   = (o >> 12) & 7;
        int khw = o >> 15;                        // [0,9)
        int ci  = s * 32 + c4 * 8 + ci8;
        int kh  = khw / 3, kw = khw - kh * 3;
        Wb[o] = f2b(Wv[((co * 256 + ci) * 3 + kh) * 3 + kw]);
    } else if (blk < 1860) {
        int i = (blk - 1600) * 256 + t;           // 66560 exactly
        if (i < 66560) {
            size_t off;
            if (i < 33792) {          // rows y=0,65
                int x = i % 66; int r = i / 66;
                int g = r & 31, rowi = (r >> 5) & 1, b = r >> 6;
                off = ((((size_t)b * 66 + rowi * 65) * 32) + g) * 66 + x;
            } else {                  // cols x=0,65 for y=1..64
                int k = i - 33792;
                int xi = k & 1; int g = (k >> 1) & 31; int y1 = (k >> 6) & 63; int b = k >> 12;
                off = ((((size_t)b * 66 + (y1 + 1)) * 32) + g) * 66 + xi * 65;
            }
            *(u16x8*)&msP[off * 8] = (u16x8){0, 0, 0, 0, 0, 0, 0, 0};
        }
    } else {
        int local = blk - 1860;        // 4096 = 8b * 64h * 8s
        int s = local & 7;
        int h = (local >> 3) & 63;
        int b = local >> 9;
        const float* src = ms + ((size_t)b * 256 + s * 32) * HW + h * 64;
        for (int l = t; l < 2048; l += 256) {
            int ci = l >> 6, w = l & 63;
            Ls[ci][w] = src[ci * HW + w];
        }
        __syncthreads();
        int w = t & 63, gi = t >> 6;   // gi in [0,4)
        u16x8 vh;
#pragma unroll
        for (int j = 0; j < 8; ++j) vh[j] = f2b(Ls[gi * 8 + j][w]);
        size_t offH = ((((size_t)b * 66 + (h + 1)) * 32) + (s * 4 + gi)) * 66 + (w + 1);
        *(u16x8*)&msP[offH * 8] = vh;
    }
}

// ---------------- KFULL: fused pipeline, one (b,h,xh) 32-px half-tile per block --
// grid 1024 = 8b*64h*2xh, block 512 (8 waves), LDS 31.4 KB.
// r17 lesson: 128 regs/thread caps occupancy at 16 waves/CU regardless of LDS/
// grid. This round halves per-wave MFMA tiles (phase A acc[7]=28 AGPR, phase B
// acc[2]=8) so the AGPR bucket drops 64->32, freeing ~96 arch VGPRs for phase C
// (~62 live) -> no spills, deeper load MLP. No work duplication (disjoint x).
__global__ __launch_bounds__(512, 4) void kfull(
    const float* __restrict__ ms, const unsigned short* __restrict__ msP,
    const unsigned short* __restrict__ Wall, const unsigned short* __restrict__ Wallo,
    const float* __restrict__ bias448, const unsigned short* __restrict__ Wb,
    const float* __restrict__ Wv_b, const float* __restrict__ ctx,
    float* __restrict__ out) {
    __shared__ unsigned char smem[32128] __attribute__((aligned(16)));
    unsigned short* qtS16 = (unsigned short*)smem;              // [128c][32px]
    unsigned short* vS16  = (unsigned short*)(smem + 8192);     // [128c][32px]
    // stage region [16384, 29696): A dbuf 8 KB / B dbuf 12.75 KB / C part 2 KB
    float* biasS  = (float*)(smem + 29696);      // 448 floats
    float* biasB  = (float*)(smem + 31488);      // 128 floats
    float* logitS = (float*)(smem + 31488);      // aliases biasB (dead by phase C)
    float* lmS    = (float*)(smem + 32000);      // 32 floats
    float (*part)[64] = (float (*)[64])(smem + 16384);

    int t = threadIdx.x;
    int lane = t & 63, wid = t >> 6;
    int c4l = lane >> 4, lrow = lane & 15;
    int blk = blockIdx.x;
    int b = blk >> 7, h = (blk >> 1) & 63, xh = blk & 1;

    // ================= Phase A: qt/lm (M=448, N=32) =================
    {
        auto Bs = (unsigned short (*)[2][4][32][8])(smem + 16384);  // [buf][plane][c4][x][ci8]
        int wm = wid >> 1, wn = wid & 1;
        int xs = t & 31, g4 = t >> 5;              // 16 groups of 2 ci
        int c4w = g4 >> 2, sub = g4 & 3;
        const float* msb = ms + ((size_t)b * 256 + g4 * 2) * HW + h * 64 + xh * 32 + xs;
        for (int i = t; i < 448; i += 512) biasS[i] = bias448[i];
        if (t < 128) biasB[t] = Wv_b[t];
        if (t < 32) lmS[t] = 0.f;

        f32x4 acc[7];
#pragma unroll
        for (int mf = 0; mf < 7; ++mf) acc[mf] = (f32x4){0.f, 0.f, 0.f, 0.f};

        const bf16x8* Whip = (const bf16x8*)Wall;
        const bf16x8* Wlop = (const bf16x8*)Wallo;

#define CVT_WRITE2(bufv, F0, F1) do {                                           \
        unsigned short h0 = f2b(F0), h1 = f2b(F1);                              \
        unsigned short q0 = f2b((F0) - b2f(h0)), q1 = f2b((F1) - b2f(h1));      \
        *(unsigned*)&Bs[bufv][0][c4w][xs][sub * 2] =                            \
            (unsigned)h0 | ((unsigned)h1 << 16);                                \
        *(unsigned*)&Bs[bufv][1][c4w][xs][sub * 2] =                            \
            (unsigned)q0 | ((unsigned)q1 << 16);                                \
    } while (0)

        {
            float f0 = msb[0], f1 = msb[HW];
            CVT_WRITE2(0, f0, f1);
        }
        __syncthreads();

        int xw = wn * 16 + lrow;                   // this wave's px in [0,32)
        for (int s = 0; s < 8; ++s) {
            int cur = s & 1;
            float fn0, fn1;
            if (s < 7) {
                const float* p = msb + (size_t)(s + 1) * 32 * HW;
                fn0 = p[0]; fn1 = p[HW];
            }
            bf16x8 bh = *(const bf16x8*)&Bs[cur][0][c4l][xw][0];
            bf16x8 bl = *(const bf16x8*)&Bs[cur][1][c4l][xw][0];
#pragma unroll
            for (int mf = 0; mf < 7; ++mf) {
                size_t widx = (size_t)(s * 4 + c4l) * 448 + wm * 112 + mf * 16 + lrow;
                bf16x8 ah = Whip[widx];
                bf16x8 al = Wlop[widx];
                acc[mf] = __builtin_amdgcn_mfma_f32_16x16x32_bf16(ah, bh, acc[mf], 0, 0, 0);
                acc[mf] = __builtin_amdgcn_mfma_f32_16x16x32_bf16(ah, bl, acc[mf], 0, 0, 0);
                acc[mf] = __builtin_amdgcn_mfma_f32_16x16x32_bf16(al, bh, acc[mf], 0, 0, 0);
            }
            if (s < 7) CVT_WRITE2(cur ^ 1, fn0, fn1);
            __syncthreads();
        }
#undef CVT_WRITE2

        float lmp = 0.f;
#pragma unroll
        for (int mf = 0; mf < 7; ++mf) {
            int base = wm * 112 + mf * 16;
            int r0 = base + c4l * 4;
            f32x4 v = acc[mf];
            if (base < 128) {
#pragma unroll
                for (int j = 0; j < 4; ++j)
                    qtS16[(r0 + j) * 32 + xw] = f2b(v[j] + biasS[r0 + j]);
            } else {
                lmp += (v[0] + biasS[r0]) * (v[1] + biasS[r0 + 1])
                     + (v[2] + biasS[r0 + 2]) * (v[3] + biasS[r0 + 3]);
            }
        }
        if (wm != 0) {
            lmp += __shfl_xor(lmp, 16);
            lmp += __shfl_xor(lmp, 32);
            if (c4l == 0) atomicAdd(&lmS[xw], lmp);
        }
    }

    // ================= Phase B: 3x3 conv (M=128, N=32) =================
    {
        auto Bs2 = (unsigned short (*)[3264])(smem + 16384);   // [buf][408 chunks * 8]
        int wm = wid >> 1, wn = wid & 1;

        f32x4 acc[2];
#pragma unroll
        for (int mf = 0; mf < 2; ++mf) acc[mf] = (f32x4){0.f, 0.f, 0.f, 0.f};

        const bf16x8* Wbp = (const bf16x8*)Wb;

#define STAGE2(bufv, sv) do {                                                       \
        if (t < 408) {                                                              \
            int rc = t / 34; int x = t - rc * 34;                                   \
            int r = rc >> 2, c4 = rc & 3;                                           \
            int y = h + r;                          /* msP rows h-1..h+1 */         \
            const unsigned short* gp = msP +                                        \
                (((((size_t)b * 66 + y) * 32) + ((sv) * 4 + c4)) * 66               \
                 + xh * 32 + x) * 8;                                                \
            __builtin_amdgcn_global_load_lds(                                       \
                (const __attribute__((address_space(1))) void*)gp,                  \
                (__attribute__((address_space(3))) void*)&Bs2[bufv][t * 8],         \
                16, 0, 0);                                                          \
        }                                                                           \
    } while (0)

        __syncthreads();   // phase-A stage region dead
        STAGE2(0, 0);
        __syncthreads();

        for (int s = 0; s < 8; ++s) {
            int cur = s & 1;
            if (s < 7) STAGE2(cur ^ 1, s + 1);
#pragma unroll
            for (int khw = 0; khw < 9; ++khw) {
                int kh = khw / 3, kw = khw - 3 * (khw / 3);
                bf16x8 bf;
                {
                    int chunk = (kh * 4 + c4l) * 34 + wn * 16 + lrow + kw;
                    bf = *(const bf16x8*)&Bs2[cur][chunk * 8];
                }
#pragma unroll
                for (int mf = 0; mf < 2; ++mf) {
                    bf16x8 a = Wbp[((khw * 8 + s) * 4 + c4l) * 128 + wm * 32 + mf * 16 + lrow];
                    acc[mf] = __builtin_amdgcn_mfma_f32_16x16x32_bf16(a, bf, acc[mf], 0, 0, 0);
                }
            }
            __syncthreads();
        }
#undef STAGE2

        int x = wn * 16 + lrow;
#pragma unroll
        for (int mf = 0; mf < 2; ++mf) {
            int co0 = wm * 32 + mf * 16 + c4l * 4;
            f32x4 v = acc[mf];
#pragma unroll
            for (int j = 0; j < 4; ++j)
                vS16[(co0 + j) * 32 + x] = f2b(v[j] + biasB[co0 + j]);
        }
    }

    // ================= Phase C: online-softmax combine =================
    __syncthreads();   // qtS, vS, lmS all visible
    {
        const unsigned* qtS32 = (const unsigned*)qtS16;
        const unsigned* vS32  = (const unsigned*)vS16;
        int xg = t & 15, cq = t >> 4;     // 16 x-groups of 4 outcols, 32 c-groups of 4
        int wv = t >> 6;
        unsigned qp[4], vp[4];
#pragma unroll
        for (int j = 0; j < 4; ++j) {
            qp[j] = qtS32[(cq * 4 + j) * 16 + xg];
            vp[j] = vS32[(cq * 4 + j) * 16 + xg];
        }
        float lmx0 = lmS[xg * 2], lmx1 = lmS[xg * 2 + 1];

        for (int yi = 0; yi < 2; ++yi) {
            int y = 2 * h + yi;
            float m[4] = {lmx0, lmx0, lmx1, lmx1};
            float sum[4] = {1.f, 1.f, 1.f, 1.f};
            float4 oa[4];
#pragma unroll
            for (int j = 0; j < 4; ++j) {
                float vx = b2f((unsigned short)(vp[j] & 0xffffu));
                float vy = b2f((unsigned short)(vp[j] >> 16));
                oa[j] = (float4){vx, vx, vy, vy};
            }
#pragma unroll 1
            for (int n = 0; n < 3; ++n) {
                const float* cb = ctx + ((size_t)(n * 8 + b) * 128 + cq * 4) * YX
                                  + (size_t)y * 128 + xh * 64 + xg * 4;
                float4 cx[4];
#pragma unroll
                for (int j = 0; j < 4; ++j) cx[j] = *(const float4*)&cb[(size_t)j * YX];
                float lp[4] = {0.f, 0.f, 0.f, 0.f};
#pragma unroll
                for (int j = 0; j < 4; ++j) {
                    float qx = b2f((unsigned short)(qp[j] & 0xffffu));
                    float qy = b2f((unsigned short)(qp[j] >> 16));
                    lp[0] += cx[j].x * qx;
                    lp[1] += cx[j].y * qx;
                    lp[2] += cx[j].z * qy;
                    lp[3] += cx[j].w * qy;
                }
#pragma unroll
                for (int xl = 0; xl < 4; ++xl) {
                    lp[xl] += __shfl_xor(lp[xl], 16);
                    lp[xl] += __shfl_xor(lp[xl], 32);
                }
                __syncthreads();   // prior logitS reads / part usage complete
                if (lane < 16) {
#pragma unroll
                    for (int xl = 0; xl < 4; ++xl) part[wv][xg * 4 + xl] = lp[xl];
                }
                __syncthreads();
                if (t < 64) {
                    float s = 0.f;
#pragma unroll
                    for (int w = 0; w < 8; ++w) s += part[w][t];
                    logitS[t] = s;
                }
                __syncthreads();
                float f[4], e[4];
#pragma unroll
                for (int xl = 0; xl < 4; ++xl) {
                    float ln = logitS[xg * 4 + xl];
                    float nm = fmaxf(m[xl], ln);
                    f[xl] = __expf(m[xl] - nm);
                    e[xl] = __expf(ln - nm);
                    sum[xl] = sum[xl] * f[xl] + e[xl];
                    m[xl] = nm;
                }
#pragma unroll
                for (int j = 0; j < 4; ++j) {
                    oa[j].x = oa[j].x * f[0] + e[0] * cx[j].x;
                    oa[j].y = oa[j].y * f[1] + e[1] * cx[j].y;
                    oa[j].z = oa[j].z * f[2] + e[2] * cx[j].z;
                    oa[j].w = oa[j].w * f[3] + e[3] * cx[j].w;
                }
            }
            float r0 = 1.f / sum[0], r1 = 1.f / sum[1], r2 = 1.f / sum[2], r3 = 1.f / sum[3];
            float* obase = out + ((size_t)b * 128 + cq * 4) * YX
                           + (size_t)y * 128 + xh * 64 + xg * 4;
#pragma unroll
            for (int j = 0; j < 4; ++j) {
                float4 o;
                o.x = oa[j].x * r0;
                o.y = oa[j].y * r1;
                o.z = oa[j].z * r2;
                o.w = oa[j].w * r3;
                *(float4*)&obase[(size_t)j * YX] = o;
            }
        }
    }
}

extern "C" void kernel_launch(void* const* d_in, const int* in_sizes, int n_in,
                              void* d_out, int out_size, void* d_ws, size_t ws_size,
                              hipStream_t stream) {
    const float* ctx  = (const float*)d_in[0];
    const float* ms   = (const float*)d_in[1];
    const float* Wc_w = (const float*)d_in[2];
    const float* Wc_b = (const float*)d_in[3];
    const float* Wf_w = (const float*)d_in[4];
    const float* Wf_b = (const float*)d_in[5];
    const float* Wk_w = (const float*)d_in[6];
    const float* Wk_b = (const float*)d_in[7];
    const float* Wv_w = (const float*)d_in[8];
    const float* Wv_b = (const float*)d_in[9];
    float* out = (float*)d_out;
    float* ws = (float*)d_ws;
    float* bias448 = ws + WS_BIAS;
    unsigned short* Wallp  = (unsigned short*)(ws + WS_WALL);
    unsigned short* Wallop = (unsigned short*)(ws + WS_WALLO);
    unsigned short* msPp   = (unsigned short*)(ws + WS_MSP);
    unsigned short* Wbp    = (unsigned short*)(ws + WS_WB);

    hipLaunchKernelGGL(k0, dim3(5956), dim3(256), 0, stream, Wc_w, Wc_b, Wf_w, Wf_b,
                       Wk_w, Wk_b, Wv_w, ms, Wallp, Wallop, bias448, Wbp, msPp);
    hipLaunchKernelGGL(kfull, dim3(1024), dim3(512), 0, stream, ms, msPp, Wallp, Wallop,
                       bias448, Wbp, Wv_b, ctx, out);
}